// Round 9
// baseline (393.013 us; speedup 1.0000x reference)
//
#include <hip/hip_runtime.h>

#define NA 50000
#define NT 25000
#define EAA 800000
#define EAT 400000
#define ETA 400000
#define NSEG 125000          // NA + NA + NT rows: [aa | ta | at]
#define TOTAL_E 1600000
#define NB 489               // scan blocks of 256 rows
#define NBLK_E 1563          // ceil(1600000/1024): 1 thread/edge kernels
#define DDEG_STRIDE 125024   // per-copy dst-degree stride
#define SRCH_STRIDE 75008    // per-copy src-histogram stride: at[50000] | ta[25000] | pad

// conv1 gather: 512 blocks x 1024 threads persistent
#define C1_AB 390            // agent blocks (16 waves each -> 6240 agent wave-streams)
#define C1_TB 122            // target blocks
#define C1_AS (C1_AB * 16)
#define C1_TS (C1_TB * 16)

// dense-B grid
#define NBB_A 782            // ceil(50000/64)
#define NBB_T 391            // ceil(25000/64)

// ---- workspace layout (4-byte element offsets) ----
// CURP: ONE CURSOR PER 64B CACHELINE (row*16). R5's 110us scatter disaster was 16
// cursors/line -> ~100-deep return-atomic queues; padding leaves only true same-row
// contention (avg 12.8). No REC intermediate at all (R8 showed its scattered partial-line
// writes ran at ~1TB/s and dominated p1).
#define O_DDEG    0          // int[8*125024]: 8 striped dst-degree histograms
#define O_SRCH    1000192    // int[8*75008]: 8 striped src-degree histograms (contiguous w/ DDEG)
#define O_BTOT    1600256    // int[512]: per-bucket totals
#define O_RDEG    1600768    // int[125000]: row degrees
#define O_RO      1725768    // int[125001]: CSR row offsets
#define O_CURP    1850784    // int[125000*16]: padded scatter cursors (1/cacheline)
#define O_CAA     3850784    // float[50000]: rsqrt(indeg_aa+1)
#define O_CTAD    3900784    // float[50000]
#define O_CATD    3950784    // float[25000]
#define O_CATS    3975784    // float[50000]
#define O_CTAS    4025784    // float[25000]
#define O_U       4050784    // float[512]
#define O_P       4051296    // float[100000]
#define O_Q       4151296    // float[100000]
#define O_R       4251296    // float[50000]
#define O_CSR     4301296    // ushort[1600000] = 800000 ints
#define O_AGA     5101296    // float[50000*64]  (agent agg: [ci*(aggA+self) | ctd*aggT])
#define O_AGT     8301296    // float[25000*32]  (target agg: catd*aggAT)

__device__ __forceinline__ float bcast(float v, int l) {
    return __int_as_float(__builtin_amdgcn_readlane(__float_as_int(v), l));
}

// ---------- deg: 1 thread/edge, fire-and-forget striped global atomics ----------
__global__ void __launch_bounds__(1024)
deg_kernel(const int* __restrict__ src_aa, const int* __restrict__ dst_aa,
           const int* __restrict__ src_ta, const int* __restrict__ dst_ta,
           const int* __restrict__ src_at, const int* __restrict__ dst_at,
           int* __restrict__ wi) {
    int t = blockIdx.x * 1024 + threadIdx.x;
    if (t >= TOTAL_E) return;
    int c = blockIdx.x & 7;
    int* ddeg = wi + O_DDEG + c * DDEG_STRIDE;
    int* srch = wi + O_SRCH + c * SRCH_STRIDE;
    int row;
    if (t < EAA) {
        row = dst_aa[t];
    } else if (t < EAA + ETA) {
        int u = t - EAA;
        row = NA + dst_ta[u];
        atomicAdd(&srch[50000 + src_ta[u]], 1);
    } else {
        int u = t - EAA - ETA;
        row = 2 * NA + dst_at[u];
        atomicAdd(&srch[src_at[u]], 1);
    }
    atomicAdd(&ddeg[row], 1);
}

// ---------- btot: sum 8 deg copies -> rowdeg + per-bucket totals ----------
__global__ void __launch_bounds__(256)
btot_kernel(int* __restrict__ wi) {
    __shared__ int ws[4];
    int k = blockIdx.x, tid = threadIdx.x, lane = tid & 63, w = tid >> 6;
    int g = k * 256 + tid;
    int d = 0;
    if (g < NSEG) {
#pragma unroll
        for (int c = 0; c < 8; ++c) d += wi[O_DDEG + c * DDEG_STRIDE + g];
        wi[O_RDEG + g] = d;
    }
    int a = d;
#pragma unroll
    for (int m = 32; m; m >>= 1) a += __shfl_xor(a, m, 64);
    if (lane == 0) ws[w] = a;
    __syncthreads();
    if (tid == 0) wi[O_BTOT + k] = ws[0] + ws[1] + ws[2] + ws[3];
}

// ---------- scan + coefs + aux: blocks 0..NB-1 = row scan; NB..NB+73 = src coefs; NB+74 = U ----------
__global__ void __launch_bounds__(1024)
scan_aux_kernel(int* __restrict__ wi, float* __restrict__ wf,
                const float* __restrict__ W2_aa, const float* __restrict__ W2_ta,
                const float* __restrict__ W2_at, const float* __restrict__ b2_aa,
                const float* __restrict__ b2_ta, const float* __restrict__ b2_at,
                const float* __restrict__ Wp_a, const float* __restrict__ bp_a,
                const float* __restrict__ Wp_t, const float* __restrict__ bp_t) {
    int bb = blockIdx.x, tid = threadIdx.x, lane = tid & 63, wid = tid >> 6;
    if (bb < NB) {
        int* ro = wi + O_RO;
        float* caa = wf + O_CAA;
        float* ctad = wf + O_CTAD;
        float* catd = wf + O_CATD;
        __shared__ int wsum[16];
        int k = bb;
        // g0 = sum of BTOT[0..k)
        int a = (tid < k) ? wi[O_BTOT + tid] : 0;
#pragma unroll
        for (int m = 32; m; m >>= 1) a += __shfl_xor(a, m, 64);
        if (lane == 0) wsum[wid] = a;
        __syncthreads();
        int g0 = 0;
#pragma unroll
        for (int w = 0; w < 16; ++w) g0 += wsum[w];
        __syncthreads();   // protect wsum reuse by scan below
        int g = k * 256 + tid;
        int v = 0, x = 0;
        if (tid < 256) {
            if (g < NSEG) v = wi[O_RDEG + g];
            x = v;
#pragma unroll
            for (int off = 1; off < 64; off <<= 1) {
                int y = __shfl_up(x, off, 64);
                if (lane >= off) x += y;
            }
            if (lane == 63) wsum[wid] = x;
        }
        __syncthreads();
        if (tid < 256) {
            int wpre = 0;
            for (int w = 0; w < wid; ++w) wpre += wsum[w];
            int excl = x - v + wpre;
            if (g < NSEG) {
                int base = g0 + excl;
                ro[g] = base;
                wi[O_CURP + g * 16] = base;    // padded scatter cursor (1/line)
                if (g < NA) caa[g] = rsqrtf((float)v + 1.0f);
                else if (g < 2 * NA) ctad[g - NA] = v > 0 ? rsqrtf((float)v) : 0.0f;
                else catd[g - 2 * NA] = v > 0 ? rsqrtf((float)v) : 0.0f;
            }
            if (k == NB - 1 && tid == 0) ro[NSEG] = TOTAL_E;
        }
    } else if (bb < NB + 74) {
        int t = (bb - NB) * 1024 + tid;
        if (t < 75000) {
            int d = 0;
#pragma unroll
            for (int c = 0; c < 8; ++c) d += wi[O_SRCH + c * SRCH_STRIDE + t];
            float v = d > 0 ? rsqrtf((float)d) : 0.0f;
            if (t < 50000) wf[O_CATS + t] = v;
            else           wf[O_CTAS + (t - 50000)] = v;
        }
    } else {
        float* U = wf + O_U;
        int t = tid;
        if (t < 128) {
            int k = t >> 1, j = t & 1;
            float a = 0.f;
            for (int f = 0; f < 64; ++f) a = fmaf(W2_aa[k * 64 + f], Wp_a[f * 2 + j], a);
            U[t] = a;
        } else if (t < 256) {
            int u = t - 128; int k = u >> 1, j = u & 1;
            float a = 0.f;
            for (int f = 0; f < 64; ++f) a = fmaf(W2_ta[k * 64 + f], Wp_a[f * 2 + j], a);
            U[128 + u] = a;
        } else if (t < 384) {
            int u = t - 256; int k = u >> 1, j = u & 1;
            float a = 0.f;
            for (int f = 0; f < 64; ++f) a = fmaf(W2_at[k * 64 + f], Wp_t[f * 2 + j], a);
            U[256 + u] = a;
        } else if (t < 386) {
            int j = t - 384;
            float a = bp_a[j];
            for (int f = 0; f < 64; ++f) a = fmaf(b2_aa[f] + b2_ta[f], Wp_a[f * 2 + j], a);
            U[384 + j] = a;
        } else if (t < 388) {
            int j = t - 386;
            float a = bp_t[j];
            for (int f = 0; f < 64; ++f) a = fmaf(b2_at[f], Wp_t[f * 2 + j], a);
            U[386 + j] = a;
        }
    }
}

// ---------- place: 1 thread/edge, padded-cursor return-atomic + ushort CSR store ----------
__global__ void __launch_bounds__(1024)
place_kernel(const int* __restrict__ src_aa, const int* __restrict__ dst_aa,
             const int* __restrict__ src_ta, const int* __restrict__ dst_ta,
             const int* __restrict__ src_at, const int* __restrict__ dst_at,
             int* __restrict__ wi) {
    int t = blockIdx.x * 1024 + threadIdx.x;
    if (t >= TOTAL_E) return;
    int row, s;
    if (t < EAA) {
        row = dst_aa[t]; s = src_aa[t];
    } else if (t < EAA + ETA) {
        int u = t - EAA;
        row = NA + dst_ta[u]; s = src_ta[u];
    } else {
        int u = t - EAA - ETA;
        row = 2 * NA + dst_at[u]; s = src_at[u];
    }
    int pos = atomicAdd(&wi[O_CURP + row * 16], 1);
    ((unsigned short*)(wi + O_CSR))[pos] = (unsigned short)s;
}

// ---------- conv1 kernel A: GATHER ONLY -> scaled agg rows to workspace. ----------
__global__ void __launch_bounds__(1024, 4)
conv1_gather_kernel(const float* __restrict__ x_a, const float* __restrict__ x_t,
                    const int* __restrict__ ro, const unsigned short* __restrict__ csr,
                    const float* __restrict__ c_aa, const float* __restrict__ c_ta_d,
                    const float* __restrict__ c_ta_s, const float* __restrict__ c_at_s,
                    const float* __restrict__ c_at_d,
                    float* __restrict__ agg_a, float* __restrict__ agg_t) {
    int lane = threadIdx.x & 63;
    int wid = threadIdx.x >> 6;      // 0..15
    int e8 = lane >> 3, k4 = lane & 7;

    if (blockIdx.x < C1_AB) {
        // ---------- agents ----------
        int i = blockIdx.x * 16 + wid;
        int b0 = ro[i], e0v = ro[i + 1];
        int b1 = ro[NA + i], e1v = ro[NA + i + 1];
        int na = e0v - b0, nt = e1v - b1;
        int sA = (lane < na) ? (int)csr[b0 + lane] : -1;
        int sT = (lane < nt) ? (int)csr[b1 + lane] : -1;
        float cAv = (sA >= 0) ? c_aa[sA] : 0.f;
        float cTv = (sT >= 0) ? c_ta_s[sT] : 0.f;

        while (true) {
            int ni = i + C1_AS;
            bool more = ni < NA;
            int nb0 = 0, ne0 = 0, nb1 = 0, ne1 = 0;
            if (more) {
                nb0 = ro[ni]; ne0 = ro[ni + 1];
                nb1 = ro[NA + ni]; ne1 = ro[NA + ni + 1];
            }
            float ci = c_aa[i], ctd = c_ta_d[i];
            float4 xs = make_float4(0.f, 0.f, 0.f, 0.f);
            if (e8 == 0) xs = *(const float4*)(x_a + (size_t)i * 32 + k4 * 4);

            float4 accA = make_float4(0.f, 0.f, 0.f, 0.f);
            float4 accT = make_float4(0.f, 0.f, 0.f, 0.f);
            int nGA = (min(na, 64) + 7) >> 3;
            int nGT = (min(nt, 64) + 7) >> 3;
            int ga = 0;
            for (; ga + 2 <= nGA; ga += 2) {
                int s0 = __shfl(sA, ga * 8 + e8, 64);
                int s1 = __shfl(sA, ga * 8 + 8 + e8, 64);
                float w0 = __shfl(cAv, ga * 8 + e8, 64);
                float w1 = __shfl(cAv, ga * 8 + 8 + e8, 64);
                float4 x0 = make_float4(0.f, 0.f, 0.f, 0.f), x1 = x0;
                if (s0 >= 0) x0 = *(const float4*)(x_a + (size_t)s0 * 32 + k4 * 4);
                if (s1 >= 0) x1 = *(const float4*)(x_a + (size_t)s1 * 32 + k4 * 4);
                accA.x = fmaf(x0.x, w0, accA.x); accA.y = fmaf(x0.y, w0, accA.y);
                accA.z = fmaf(x0.z, w0, accA.z); accA.w = fmaf(x0.w, w0, accA.w);
                accA.x = fmaf(x1.x, w1, accA.x); accA.y = fmaf(x1.y, w1, accA.y);
                accA.z = fmaf(x1.z, w1, accA.z); accA.w = fmaf(x1.w, w1, accA.w);
            }
            if (ga < nGA) {
                int s0 = __shfl(sA, ga * 8 + e8, 64);
                float w0 = __shfl(cAv, ga * 8 + e8, 64);
                float4 x0 = make_float4(0.f, 0.f, 0.f, 0.f);
                if (s0 >= 0) x0 = *(const float4*)(x_a + (size_t)s0 * 32 + k4 * 4);
                accA.x = fmaf(x0.x, w0, accA.x); accA.y = fmaf(x0.y, w0, accA.y);
                accA.z = fmaf(x0.z, w0, accA.z); accA.w = fmaf(x0.w, w0, accA.w);
            }
            for (int j = b0 + 64 + e8; j < e0v; j += 8) {
                int s = csr[j];
                float w = c_aa[s];
                float4 xv = *(const float4*)(x_a + (size_t)s * 32 + k4 * 4);
                accA.x = fmaf(xv.x, w, accA.x); accA.y = fmaf(xv.y, w, accA.y);
                accA.z = fmaf(xv.z, w, accA.z); accA.w = fmaf(xv.w, w, accA.w);
            }
            int gt = 0;
            for (; gt + 2 <= nGT; gt += 2) {
                int s0 = __shfl(sT, gt * 8 + e8, 64);
                int s1 = __shfl(sT, gt * 8 + 8 + e8, 64);
                float w0 = __shfl(cTv, gt * 8 + e8, 64);
                float w1 = __shfl(cTv, gt * 8 + 8 + e8, 64);
                float4 x0 = make_float4(0.f, 0.f, 0.f, 0.f), x1 = x0;
                if (s0 >= 0) x0 = *(const float4*)(x_t + (size_t)s0 * 32 + k4 * 4);
                if (s1 >= 0) x1 = *(const float4*)(x_t + (size_t)s1 * 32 + k4 * 4);
                accT.x = fmaf(x0.x, w0, accT.x); accT.y = fmaf(x0.y, w0, accT.y);
                accT.z = fmaf(x0.z, w0, accT.z); accT.w = fmaf(x0.w, w0, accT.w);
                accT.x = fmaf(x1.x, w1, accT.x); accT.y = fmaf(x1.y, w1, accT.y);
                accT.z = fmaf(x1.z, w1, accT.z); accT.w = fmaf(x1.w, w1, accT.w);
            }
            if (gt < nGT) {
                int s0 = __shfl(sT, gt * 8 + e8, 64);
                float w0 = __shfl(cTv, gt * 8 + e8, 64);
                float4 x0 = make_float4(0.f, 0.f, 0.f, 0.f);
                if (s0 >= 0) x0 = *(const float4*)(x_t + (size_t)s0 * 32 + k4 * 4);
                accT.x = fmaf(x0.x, w0, accT.x); accT.y = fmaf(x0.y, w0, accT.y);
                accT.z = fmaf(x0.z, w0, accT.z); accT.w = fmaf(x0.w, w0, accT.w);
            }
            for (int j = b1 + 64 + e8; j < e1v; j += 8) {
                int s = csr[j];
                float w = c_ta_s[s];
                float4 xv = *(const float4*)(x_t + (size_t)s * 32 + k4 * 4);
                accT.x = fmaf(xv.x, w, accT.x); accT.y = fmaf(xv.y, w, accT.y);
                accT.z = fmaf(xv.z, w, accT.z); accT.w = fmaf(xv.w, w, accT.w);
            }
            // self-loop
            accA.x = fmaf(xs.x, ci, accA.x); accA.y = fmaf(xs.y, ci, accA.y);
            accA.z = fmaf(xs.z, ci, accA.z); accA.w = fmaf(xs.w, ci, accA.w);

            int nsA = -1, nsT = -1;
            if (more) {
                int nna = ne0 - nb0, nnt = ne1 - nb1;
                nsA = (lane < nna) ? (int)csr[nb0 + lane] : -1;
                nsT = (lane < nnt) ? (int)csr[nb1 + lane] : -1;
            }

#pragma unroll
            for (int m = 8; m <= 32; m <<= 1) {
                accA.x += __shfl_xor(accA.x, m, 64);
                accA.y += __shfl_xor(accA.y, m, 64);
                accA.z += __shfl_xor(accA.z, m, 64);
                accA.w += __shfl_xor(accA.w, m, 64);
                accT.x += __shfl_xor(accT.x, m, 64);
                accT.y += __shfl_xor(accT.y, m, 64);
                accT.z += __shfl_xor(accT.z, m, 64);
                accT.w += __shfl_xor(accT.w, m, 64);
            }

            float ncA = 0.f, ncT = 0.f;
            if (more) {
                ncA = (nsA >= 0) ? c_aa[nsA] : 0.f;
                ncT = (nsT >= 0) ? c_ta_s[nsT] : 0.f;
            }

            if (e8 == 0) {
                *(float4*)(agg_a + (size_t)i * 64 + k4 * 4) =
                    make_float4(accA.x * ci, accA.y * ci, accA.z * ci, accA.w * ci);
                *(float4*)(agg_a + (size_t)i * 64 + 32 + k4 * 4) =
                    make_float4(accT.x * ctd, accT.y * ctd, accT.z * ctd, accT.w * ctd);
            }

            if (!more) break;
            i = ni;
            b0 = nb0; e0v = ne0; b1 = nb1; e1v = ne1;
            na = ne0 - nb0; nt = ne1 - nb1;
            sA = nsA; sT = nsT; cAv = ncA; cTv = ncT;
        }
    } else {
        // ---------- targets ----------
        int i = (blockIdx.x - C1_AB) * 16 + wid;
        int b0 = ro[2 * NA + i], e0v = ro[2 * NA + i + 1];
        int na = e0v - b0;
        int sA = (lane < na) ? (int)csr[b0 + lane] : -1;
        float cAv = (sA >= 0) ? c_at_s[sA] : 0.f;

        while (true) {
            int ni = i + C1_TS;
            bool more = ni < NT;
            int nb0 = 0, ne0 = 0;
            if (more) { nb0 = ro[2 * NA + ni]; ne0 = ro[2 * NA + ni + 1]; }
            float cd = c_at_d[i];

            float4 acc = make_float4(0.f, 0.f, 0.f, 0.f);
            int nG = (min(na, 64) + 7) >> 3;
            int ga = 0;
            for (; ga + 2 <= nG; ga += 2) {
                int s0 = __shfl(sA, ga * 8 + e8, 64);
                int s1 = __shfl(sA, ga * 8 + 8 + e8, 64);
                float w0 = __shfl(cAv, ga * 8 + e8, 64);
                float w1 = __shfl(cAv, ga * 8 + 8 + e8, 64);
                float4 x0 = make_float4(0.f, 0.f, 0.f, 0.f), x1 = x0;
                if (s0 >= 0) x0 = *(const float4*)(x_a + (size_t)s0 * 32 + k4 * 4);
                if (s1 >= 0) x1 = *(const float4*)(x_a + (size_t)s1 * 32 + k4 * 4);
                acc.x = fmaf(x0.x, w0, acc.x); acc.y = fmaf(x0.y, w0, acc.y);
                acc.z = fmaf(x0.z, w0, acc.z); acc.w = fmaf(x0.w, w0, acc.w);
                acc.x = fmaf(x1.x, w1, acc.x); acc.y = fmaf(x1.y, w1, acc.y);
                acc.z = fmaf(x1.z, w1, acc.z); acc.w = fmaf(x1.w, w1, acc.w);
            }
            if (ga < nG) {
                int s0 = __shfl(sA, ga * 8 + e8, 64);
                float w0 = __shfl(cAv, ga * 8 + e8, 64);
                float4 x0 = make_float4(0.f, 0.f, 0.f, 0.f);
                if (s0 >= 0) x0 = *(const float4*)(x_a + (size_t)s0 * 32 + k4 * 4);
                acc.x = fmaf(x0.x, w0, acc.x); acc.y = fmaf(x0.y, w0, acc.y);
                acc.z = fmaf(x0.z, w0, acc.z); acc.w = fmaf(x0.w, w0, acc.w);
            }
            for (int j = b0 + 64 + e8; j < e0v; j += 8) {
                int s = csr[j];
                float w = c_at_s[s];
                float4 xv = *(const float4*)(x_a + (size_t)s * 32 + k4 * 4);
                acc.x = fmaf(xv.x, w, acc.x); acc.y = fmaf(xv.y, w, acc.y);
                acc.z = fmaf(xv.z, w, acc.z); acc.w = fmaf(xv.w, w, acc.w);
            }

            int nsA = -1;
            if (more) {
                int nna = ne0 - nb0;
                nsA = (lane < nna) ? (int)csr[nb0 + lane] : -1;
            }

#pragma unroll
            for (int m = 8; m <= 32; m <<= 1) {
                acc.x += __shfl_xor(acc.x, m, 64);
                acc.y += __shfl_xor(acc.y, m, 64);
                acc.z += __shfl_xor(acc.z, m, 64);
                acc.w += __shfl_xor(acc.w, m, 64);
            }

            float ncA = 0.f;
            if (more) ncA = (nsA >= 0) ? c_at_s[nsA] : 0.f;

            if (e8 == 0) {
                *(float4*)(agg_t + (size_t)i * 32 + k4 * 4) =
                    make_float4(acc.x * cd, acc.y * cd, acc.z * cd, acc.w * cd);
            }

            if (!more) break;
            i = ni;
            b0 = nb0; e0v = ne0; na = ne0 - nb0;
            sA = nsA; cAv = ncA;
        }
    }
}

// ---------- kernel B: dense transform + fused projection ----------
__global__ void __launch_bounds__(256)
dense_b_kernel(const float* __restrict__ agg_a, const float* __restrict__ agg_t,
               const float* __restrict__ W_aa, const float* __restrict__ W_ta,
               const float* __restrict__ W_at,
               const float* __restrict__ b_aa, const float* __restrict__ b_ta,
               const float* __restrict__ b_at, const float* __restrict__ U,
               const float* __restrict__ c_aa, const float* __restrict__ c_at_s,
               const float* __restrict__ c_ta_s,
               float* __restrict__ p, float* __restrict__ q, float* __restrict__ r) {
    __shared__ float Wc[64 * 68];    // Wc[k*68+f]
    __shared__ float AG[64 * 68];    // AG[n*68+k]
    __shared__ float BI[64];
    __shared__ float UP0[64], UP1[64], UQ0[64], UQ1[64];
    int t = threadIdx.x;
    int nloc = t >> 2;               // 0..63: node within tile
    int f0 = (t & 3) << 4;           // 0,16,32,48

    if (blockIdx.x < NBB_A) {
        for (int idx = t; idx < 4096; idx += 256) {
            int k = idx >> 6, f = idx & 63;
            Wc[k * 68 + f] = (k < 32) ? W_aa[k * 64 + f] : W_ta[(k - 32) * 64 + f];
        }
        if (t < 64) {
            BI[t] = b_aa[t] + b_ta[t];
            UP0[t] = U[t * 2];       UP1[t] = U[t * 2 + 1];
            UQ0[t] = U[256 + t * 2]; UQ1[t] = U[256 + t * 2 + 1];
        }
        int t0 = blockIdx.x * 64;
        for (int idx = t; idx < 1024; idx += 256) {
            int n = idx >> 4, kq = idx & 15;
            int gi = t0 + n;
            float4 v = make_float4(0.f, 0.f, 0.f, 0.f);
            if (gi < NA) v = *(const float4*)(agg_a + (size_t)gi * 64 + kq * 4);
            *(float4*)&AG[n * 68 + kq * 4] = v;
        }
        __syncthreads();

        float4 h0 = *(const float4*)&BI[f0];
        float4 h1 = *(const float4*)&BI[f0 + 4];
        float4 h2 = *(const float4*)&BI[f0 + 8];
        float4 h3 = *(const float4*)&BI[f0 + 12];
        const float* ag = &AG[nloc * 68];
#pragma unroll 8
        for (int k = 0; k < 64; ++k) {
            float a = ag[k];
            const float* w = &Wc[k * 68 + f0];
            float4 w0 = *(const float4*)(w);
            float4 w1 = *(const float4*)(w + 4);
            float4 w2 = *(const float4*)(w + 8);
            float4 w3 = *(const float4*)(w + 12);
            h0.x = fmaf(a, w0.x, h0.x); h0.y = fmaf(a, w0.y, h0.y);
            h0.z = fmaf(a, w0.z, h0.z); h0.w = fmaf(a, w0.w, h0.w);
            h1.x = fmaf(a, w1.x, h1.x); h1.y = fmaf(a, w1.y, h1.y);
            h1.z = fmaf(a, w1.z, h1.z); h1.w = fmaf(a, w1.w, h1.w);
            h2.x = fmaf(a, w2.x, h2.x); h2.y = fmaf(a, w2.y, h2.y);
            h2.z = fmaf(a, w2.z, h2.z); h2.w = fmaf(a, w2.w, h2.w);
            h3.x = fmaf(a, w3.x, h3.x); h3.y = fmaf(a, w3.y, h3.y);
            h3.z = fmaf(a, w3.z, h3.z); h3.w = fmaf(a, w3.w, h3.w);
        }
        float hv[16];
        hv[0] = fmaxf(h0.x, 0.f); hv[1] = fmaxf(h0.y, 0.f);
        hv[2] = fmaxf(h0.z, 0.f); hv[3] = fmaxf(h0.w, 0.f);
        hv[4] = fmaxf(h1.x, 0.f); hv[5] = fmaxf(h1.y, 0.f);
        hv[6] = fmaxf(h1.z, 0.f); hv[7] = fmaxf(h1.w, 0.f);
        hv[8] = fmaxf(h2.x, 0.f); hv[9] = fmaxf(h2.y, 0.f);
        hv[10] = fmaxf(h2.z, 0.f); hv[11] = fmaxf(h2.w, 0.f);
        hv[12] = fmaxf(h3.x, 0.f); hv[13] = fmaxf(h3.y, 0.f);
        hv[14] = fmaxf(h3.z, 0.f); hv[15] = fmaxf(h3.w, 0.f);
        float p0 = 0.f, p1 = 0.f, q0 = 0.f, q1 = 0.f;
#pragma unroll
        for (int ii = 0; ii < 16; ++ii) {
            int f = f0 + ii;
            p0 = fmaf(hv[ii], UP0[f], p0);
            p1 = fmaf(hv[ii], UP1[f], p1);
            q0 = fmaf(hv[ii], UQ0[f], q0);
            q1 = fmaf(hv[ii], UQ1[f], q1);
        }
        p0 += __shfl_xor(p0, 1, 64); p0 += __shfl_xor(p0, 2, 64);
        p1 += __shfl_xor(p1, 1, 64); p1 += __shfl_xor(p1, 2, 64);
        q0 += __shfl_xor(q0, 1, 64); q0 += __shfl_xor(q0, 2, 64);
        q1 += __shfl_xor(q1, 1, 64); q1 += __shfl_xor(q1, 2, 64);
        int gi = t0 + nloc;
        if ((t & 3) == 0 && gi < NA) {
            float ci = c_aa[gi], cq = c_at_s[gi];
            *(float2*)&p[gi * 2] = make_float2(p0 * ci, p1 * ci);
            *(float2*)&q[gi * 2] = make_float2(q0 * cq, q1 * cq);
        }
    } else {
        for (int idx = t; idx < 2048; idx += 256) {
            int k = idx >> 6, f = idx & 63;
            Wc[k * 68 + f] = W_at[k * 64 + f];
        }
        if (t < 64) {
            BI[t] = b_at[t];
            UP0[t] = U[128 + t * 2]; UP1[t] = U[128 + t * 2 + 1];
        }
        int t0 = (blockIdx.x - NBB_A) * 64;
        for (int idx = t; idx < 512; idx += 256) {
            int n = idx >> 3, kq = idx & 7;
            int gi = t0 + n;
            float4 v = make_float4(0.f, 0.f, 0.f, 0.f);
            if (gi < NT) v = *(const float4*)(agg_t + (size_t)gi * 32 + kq * 4);
            *(float4*)&AG[n * 68 + kq * 4] = v;
        }
        __syncthreads();

        float4 h0 = *(const float4*)&BI[f0];
        float4 h1 = *(const float4*)&BI[f0 + 4];
        float4 h2 = *(const float4*)&BI[f0 + 8];
        float4 h3 = *(const float4*)&BI[f0 + 12];
        const float* ag = &AG[nloc * 68];
#pragma unroll 8
        for (int k = 0; k < 32; ++k) {
            float a = ag[k];
            const float* w = &Wc[k * 68 + f0];
            float4 w0 = *(const float4*)(w);
            float4 w1 = *(const float4*)(w + 4);
            float4 w2 = *(const float4*)(w + 8);
            float4 w3 = *(const float4*)(w + 12);
            h0.x = fmaf(a, w0.x, h0.x); h0.y = fmaf(a, w0.y, h0.y);
            h0.z = fmaf(a, w0.z, h0.z); h0.w = fmaf(a, w0.w, h0.w);
            h1.x = fmaf(a, w1.x, h1.x); h1.y = fmaf(a, w1.y, h1.y);
            h1.z = fmaf(a, w1.z, h1.z); h1.w = fmaf(a, w1.w, h1.w);
            h2.x = fmaf(a, w2.x, h2.x); h2.y = fmaf(a, w2.y, h2.y);
            h2.z = fmaf(a, w2.z, h2.z); h2.w = fmaf(a, w2.w, h2.w);
            h3.x = fmaf(a, w3.x, h3.x); h3.y = fmaf(a, w3.y, h3.y);
            h3.z = fmaf(a, w3.z, h3.z); h3.w = fmaf(a, w3.w, h3.w);
        }
        float hv[16];
        hv[0] = fmaxf(h0.x, 0.f); hv[1] = fmaxf(h0.y, 0.f);
        hv[2] = fmaxf(h0.z, 0.f); hv[3] = fmaxf(h0.w, 0.f);
        hv[4] = fmaxf(h1.x, 0.f); hv[5] = fmaxf(h1.y, 0.f);
        hv[6] = fmaxf(h1.z, 0.f); hv[7] = fmaxf(h1.w, 0.f);
        hv[8] = fmaxf(h2.x, 0.f); hv[9] = fmaxf(h2.y, 0.f);
        hv[10] = fmaxf(h2.z, 0.f); hv[11] = fmaxf(h2.w, 0.f);
        hv[12] = fmaxf(h3.x, 0.f); hv[13] = fmaxf(h3.y, 0.f);
        hv[14] = fmaxf(h3.z, 0.f); hv[15] = fmaxf(h3.w, 0.f);
        float r0 = 0.f, r1 = 0.f;
#pragma unroll
        for (int ii = 0; ii < 16; ++ii) {
            int f = f0 + ii;
            r0 = fmaf(hv[ii], UP0[f], r0);
            r1 = fmaf(hv[ii], UP1[f], r1);
        }
        r0 += __shfl_xor(r0, 1, 64); r0 += __shfl_xor(r0, 2, 64);
        r1 += __shfl_xor(r1, 1, 64); r1 += __shfl_xor(r1, 2, 64);
        int gi = t0 + nloc;
        if ((t & 3) == 0 && gi < NT) {
            float cr = c_ta_s[gi];
            *(float2*)&r[gi * 2] = make_float2(r0 * cr, r1 * cr);
        }
    }
}

// ---------- conv2+proj: one wave per node, 32 edge slots x 2 comps ----------
__global__ void __launch_bounds__(256)
out_all_kernel(const float* __restrict__ p, const float* __restrict__ q,
               const float* __restrict__ r, const int* __restrict__ ro,
               const unsigned short* __restrict__ csr,
               const float* __restrict__ c_aa, const float* __restrict__ c_ta_d,
               const float* __restrict__ c_at_d, const float* __restrict__ U,
               float* __restrict__ out) {
    int wgid = blockIdx.x * 4 + (threadIdx.x >> 6);
    int lane = threadIdx.x & 63;
    int slot = lane >> 1, j = lane & 1;
    if (wgid < NA) {
        int i = wgid;
        int b0 = ro[i], n0 = ro[i + 1] - b0;
        float accA = (slot == 0) ? p[i * 2 + j] : 0.f;
        for (int e = slot; e < n0; e += 32) accA += p[(int)csr[b0 + e] * 2 + j];
        int b1 = ro[NA + i], n1 = ro[NA + i + 1] - b1;
        float accT = 0.f;
        for (int e = slot; e < n1; e += 32) accT += r[(int)csr[b1 + e] * 2 + j];
#pragma unroll
        for (int m = 2; m <= 32; m <<= 1) {
            accA += __shfl_xor(accA, m, 64);
            accT += __shfl_xor(accT, m, 64);
        }
        if (lane < 2) out[i * 2 + j] = U[384 + j] + accA * c_aa[i] + accT * c_ta_d[i];
    } else {
        int i = wgid - NA;
        int b0 = ro[2 * NA + i], n0 = ro[2 * NA + i + 1] - b0;
        float acc = 0.f;
        for (int e = slot; e < n0; e += 32) acc += q[(int)csr[b0 + e] * 2 + j];
#pragma unroll
        for (int m = 2; m <= 32; m <<= 1) acc += __shfl_xor(acc, m, 64);
        if (lane < 2) out[NA * 2 + i * 2 + j] = U[386 + j] + acc * c_at_d[i];
    }
}

extern "C" void kernel_launch(void* const* d_in, const int* in_sizes, int n_in,
                              void* d_out, int out_size, void* d_ws, size_t ws_size,
                              hipStream_t stream) {
    const float* x_a   = (const float*)d_in[1];
    const float* x_t   = (const float*)d_in[2];
    const int* src_aa  = (const int*)d_in[3];
    const int* dst_aa  = (const int*)d_in[4];
    const int* src_at  = (const int*)d_in[5];
    const int* dst_at  = (const int*)d_in[6];
    const int* src_ta  = (const int*)d_in[7];
    const int* dst_ta  = (const int*)d_in[8];
    const float* W1_aa = (const float*)d_in[9];
    const float* b1_aa = (const float*)d_in[10];
    const float* W1_at = (const float*)d_in[11];
    const float* b1_at = (const float*)d_in[12];
    const float* W1_ta = (const float*)d_in[13];
    const float* b1_ta = (const float*)d_in[14];
    const float* W2_aa = (const float*)d_in[15];
    const float* b2_aa = (const float*)d_in[16];
    const float* W2_at = (const float*)d_in[17];
    const float* b2_at = (const float*)d_in[18];
    const float* W2_ta = (const float*)d_in[19];
    const float* b2_ta = (const float*)d_in[20];
    const float* Wp_a  = (const float*)d_in[21];
    const float* bp_a  = (const float*)d_in[22];
    const float* Wp_t  = (const float*)d_in[23];
    const float* bp_t  = (const float*)d_in[24];

    int*   wi  = (int*)d_ws;
    float* wf  = (float*)d_ws;
    unsigned short* csr = (unsigned short*)(wi + O_CSR);
    float* out = (float*)d_out;

    // single memset: striped dst-degree + src-degree histograms (contiguous)
    hipMemsetAsync(wi + O_DDEG, 0,
                   (size_t)(8 * DDEG_STRIDE + 8 * SRCH_STRIDE) * 4, stream);

    // degrees via striped fire-and-forget atomics
    deg_kernel<<<NBLK_E, 1024, 0, stream>>>(src_aa, dst_aa, src_ta, dst_ta,
                                            src_at, dst_at, wi);

    // per-bucket totals + row degrees
    btot_kernel<<<NB, 256, 0, stream>>>(wi);

    // scan -> ro + PADDED cursors + dst coefs | src coefs | U fuse
    scan_aux_kernel<<<NB + 75, 1024, 0, stream>>>(wi, wf, W2_aa, W2_ta, W2_at,
                                                  b2_aa, b2_ta, b2_at,
                                                  Wp_a, bp_a, Wp_t, bp_t);

    // place edges into CSR (1 cursor per cacheline)
    place_kernel<<<NBLK_E, 1024, 0, stream>>>(src_aa, dst_aa, src_ta, dst_ta,
                                              src_at, dst_at, wi);

    // conv1-A: gather -> scaled agg rows
    conv1_gather_kernel<<<C1_AB + C1_TB, 1024, 0, stream>>>(
        x_a, x_t, wi + O_RO, csr,
        wf + O_CAA, wf + O_CTAD, wf + O_CTAS, wf + O_CATS, wf + O_CATD,
        wf + O_AGA, wf + O_AGT);

    // conv1-B: dense transform + fused projections
    dense_b_kernel<<<NBB_A + NBB_T, 256, 0, stream>>>(
        wf + O_AGA, wf + O_AGT,
        W1_aa, W1_ta, W1_at, b1_aa, b1_ta, b1_at, wf + O_U,
        wf + O_CAA, wf + O_CATS, wf + O_CTAS,
        wf + O_P, wf + O_Q, wf + O_R);

    // conv2 + projection, wave per node
    out_all_kernel<<<(NA + NT) / 4, 256, 0, stream>>>(
        wf + O_P, wf + O_Q, wf + O_R, wi + O_RO, csr,
        wf + O_CAA, wf + O_CTAD, wf + O_CATD, wf + O_U, out);
}

// Round 10
// 234.792 us; speedup vs baseline: 1.6739x; 1.6739x over previous
//
#include <hip/hip_runtime.h>

#define NA 50000
#define NT 25000
#define EAA 800000
#define EAT 400000
#define ETA 400000
#define NSEG 125000          // NA + NA + NT rows: [aa | ta | at]
#define TOTAL_E 1600000
#define NB 489               // coarse buckets of 256 rows
#define NBLK1 196            // pass-1 blocks (CHUNK=8192)
#define CHUNK 8192           // edges per pass-1 block (1024 thr x 8 reg-held edges)
#define CAP 8192             // REC slab capacity per bucket (8 sub-slabs)
#define CAP_C 1024           // per-copy sub-slab (per-stripe bucket load ~550 +- 22)
#define SRCH_STRIDE 75008    // per-copy src-histogram stride: at[50000] | ta[25000] | pad

// conv1 gather: 512 blocks x 1024 threads persistent
#define C1_AB 390            // agent blocks (16 waves each -> 6240 agent wave-streams)
#define C1_TB 122            // target blocks
#define C1_AS (C1_AB * 16)
#define C1_TS (C1_TB * 16)

// dense-B grid
#define NBB_A 782            // ceil(50000/64)
#define NBB_T 391            // ceil(25000/64)

// ---- workspace layout (4-byte element offsets) ----
// BTOT striped 8 ways: counter (c,bk) at O_BTOT + (c*NB+bk)*16 (cacheline padded).
// AGG overlays REC: REC is dead after p2_aux (stream-ordered), conv1 writes AGG after.
#define O_SRCH    0          // int[8*75008]: 8 striped src-degree histograms
#define O_BTOT    600064     // int[8*489*16]: striped+padded slab counters
#define O_RO      662656     // int[125001]: CSR row offsets
#define O_CAA     787664     // float[50000]: rsqrt(indeg_aa+1)
#define O_CTAD    837664     // float[50000]
#define O_CATD    887664     // float[25000]
#define O_CATS    912664     // float[50000]
#define O_CTAS    962664     // float[25000]
#define O_U       987664     // float[512]
#define O_P       988176     // float[100000]
#define O_Q       1088176    // float[100000]
#define O_R       1188176    // float[50000]
#define O_REC     1238176    // int[NB*CAP=4005888]: slabbed bucket-grouped records
#define O_AGA     1238176    // float[50000*64] OVERLAYS REC (dead after p2)
#define O_AGT     4438176    // float[25000*32] (ends 5238176 <= REC end 5244064)
#define O_CSR     5244064    // ushort[1600000] = 800000 ints

__device__ __forceinline__ float bcast(float v, int l) {
    return __int_as_float(__builtin_amdgcn_readlane(__float_as_int(v), l));
}

// ---------- pass 1 v4: register-held edges, no LDS sort, CHUNK=8192.
//            R9 proved the invariant is partial-line write bytes: run length per
//            (block,bucket) was 4.2 edges = 17B/64B line -> 5.6x amplification.
//            8192 edges/block -> ~16.7 edges/run ~= one full line -> amp ~1.2x.
//            Per-block write working set ~61KB; L2 holds lines until full. ----------
__global__ void __launch_bounds__(1024)
p1_fused_kernel(const int* __restrict__ src_aa, const int* __restrict__ dst_aa,
                const int* __restrict__ src_ta, const int* __restrict__ dst_ta,
                const int* __restrict__ src_at, const int* __restrict__ dst_at,
                int* __restrict__ wi) {
    __shared__ int cnt[512];                 // per-bucket count
    __shared__ int cur[512];                 // scatter cursor (starts 0)
    __shared__ int gres[512];                // reserved sub-slab base per bucket
    int b = blockIdx.x, tid = threadIdx.x;
    int* rec_g = wi + O_REC;

    for (int i = tid; i < 512; i += 1024) { cnt[i] = 0; cur[i] = 0; }
    __syncthreads();

    // phase A: load edges into REGISTERS (compile-time indices) + count (+ src degrees)
    int t0 = b * CHUNK;
    int c8 = b & 7;
    int* srch = wi + O_SRCH + c8 * SRCH_STRIDE;
    int rowr[8], srcr[8];
#pragma unroll
    for (int e = 0; e < 8; ++e) {
        int t = t0 + e * 1024 + tid;
        int row = -1, s = 0;
        if (t < TOTAL_E) {
            if (t < EAA) {
                row = dst_aa[t]; s = src_aa[t];
            } else if (t < EAA + ETA) {
                int u = t - EAA;
                row = NA + dst_ta[u]; s = src_ta[u];
                atomicAdd(&srch[50000 + s], 1);
            } else {
                int u = t - EAA - ETA;
                row = 2 * NA + dst_at[u]; s = src_at[u];
                atomicAdd(&srch[s], 1);
            }
            atomicAdd(&cnt[row >> 8], 1);
        }
        rowr[e] = row; srcr[e] = s;
    }
    __syncthreads();

    // phase D: reserve sub-slab space on striped counter (c8, bk)
    for (int bk = tid; bk < NB; bk += 1024) {
        int len = cnt[bk];
        if (len > 0) {
            int gb = atomicAdd(&wi[O_BTOT + (c8 * NB + bk) * 16], len);
            gres[bk] = bk * CAP + c8 * CAP_C + gb;
        }
    }
    __syncthreads();

    // phase E: direct scatter from registers into the sub-slab (runs ~16.7 -> full lines)
#pragma unroll
    for (int e = 0; e < 8; ++e) {
        int row = rowr[e];
        if (row >= 0) {
            int bk = row >> 8;
            int pos = atomicAdd(&cur[bk], 1);
            rec_g[gres[bk] + pos] = ((row & 255) << 16) | srcr[e];
        }
    }
}

// ---------- fused pass 2 + aux: blocks 0..NB-1 = p2 (8 sub-slabs, flattened loops);
//            NB..NB+73 = src coefs; NB+74 = U ----------
__global__ void __launch_bounds__(1024)
p2_aux_kernel(int* __restrict__ wi, float* __restrict__ wf,
              const float* __restrict__ W2_aa, const float* __restrict__ W2_ta,
              const float* __restrict__ W2_at, const float* __restrict__ b2_aa,
              const float* __restrict__ b2_ta, const float* __restrict__ b2_at,
              const float* __restrict__ Wp_a, const float* __restrict__ bp_a,
              const float* __restrict__ Wp_t, const float* __restrict__ bp_t) {
    int bb = blockIdx.x, tid = threadIdx.x, lane = tid & 63, wid = tid >> 6;
    if (bb < NB) {
        const int* rec = wi + O_REC;
        unsigned short* csr = (unsigned short*)(wi + O_CSR);
        int* ro = wi + O_RO;
        float* caa = wf + O_CAA;
        float* ctad = wf + O_CTAD;
        float* catd = wf + O_CATD;
        __shared__ int deg[256];
        __shared__ int rb[256];
        __shared__ int wsum[16];
        __shared__ int lenc[8];
        int k = bb;
        // self-compute g0 = total edges in buckets [0,k): sum all 8 copies
        int a = 0;
        if (tid < k) {
#pragma unroll
            for (int c = 0; c < 8; ++c) a += wi[O_BTOT + (c * NB + tid) * 16];
        }
#pragma unroll
        for (int m = 32; m; m >>= 1) a += __shfl_xor(a, m, 64);
        if (lane == 0) wsum[wid] = a;
        if (tid < 256) deg[tid] = 0;
        if (tid < 8) lenc[tid] = wi[O_BTOT + (tid * NB + k) * 16];
        __syncthreads();
        int g0 = 0;
#pragma unroll
        for (int w = 0; w < 16; ++w) g0 += wsum[w];
        // register-resident sub-slab prefix (compile-time indexed)
        int lp[8];
        int tot = 0;
#pragma unroll
        for (int c = 0; c < 8; ++c) { lp[c] = tot; tot += lenc[c]; }
        int s0 = k * CAP;                       // slab base
        // flattened histogram over all sub-slabs (full thread utilization)
        for (int j = tid; j < tot; j += 1024) {
            int c = 0, base = 0;
#pragma unroll
            for (int cc = 1; cc < 8; ++cc) {
                bool g = (j >= lp[cc]);
                c = g ? cc : c;
                base = g ? lp[cc] : base;
            }
            int rc = rec[s0 + c * CAP_C + (j - base)];
            atomicAdd(&deg[rc >> 16], 1);
        }
        __syncthreads();
        int v = 0, x = 0;
        if (tid < 256) {
            v = deg[tid];
            x = v;
#pragma unroll
            for (int off = 1; off < 64; off <<= 1) {
                int y = __shfl_up(x, off, 64);
                if (lane >= off) x += y;
            }
            if (lane == 63) wsum[wid] = x;
        }
        __syncthreads();
        if (tid < 256) {
            int wpre = 0;
            for (int w = 0; w < wid; ++w) wpre += wsum[w];
            int excl = x - v + wpre;
            rb[tid] = g0 + excl;
            int g = k * 256 + tid;
            if (g < NSEG) {
                ro[g] = g0 + excl;
                if (g < NA) caa[g] = rsqrtf((float)v + 1.0f);
                else if (g < 2 * NA) ctad[g - NA] = v > 0 ? rsqrtf((float)v) : 0.0f;
                else catd[g - 2 * NA] = v > 0 ? rsqrtf((float)v) : 0.0f;
            }
            if (k == NB - 1 && tid == 0) ro[NSEG] = TOTAL_E;
        }
        __syncthreads();
        // flattened scatter to CSR
        for (int j = tid; j < tot; j += 1024) {
            int c = 0, base = 0;
#pragma unroll
            for (int cc = 1; cc < 8; ++cc) {
                bool g = (j >= lp[cc]);
                c = g ? cc : c;
                base = g ? lp[cc] : base;
            }
            int rc = rec[s0 + c * CAP_C + (j - base)];
            int pos = atomicAdd(&rb[rc >> 16], 1);
            csr[pos] = (unsigned short)(rc & 0xFFFF);
        }
    } else if (bb < NB + 74) {
        int t = (bb - NB) * 1024 + tid;
        if (t < 75000) {
            int d = 0;
#pragma unroll
            for (int c = 0; c < 8; ++c) d += wi[O_SRCH + c * SRCH_STRIDE + t];
            float v = d > 0 ? rsqrtf((float)d) : 0.0f;
            if (t < 50000) wf[O_CATS + t] = v;
            else           wf[O_CTAS + (t - 50000)] = v;
        }
    } else {
        float* U = wf + O_U;
        int t = tid;
        if (t < 128) {
            int k = t >> 1, j = t & 1;
            float a = 0.f;
            for (int f = 0; f < 64; ++f) a = fmaf(W2_aa[k * 64 + f], Wp_a[f * 2 + j], a);
            U[t] = a;
        } else if (t < 256) {
            int u = t - 128; int k = u >> 1, j = u & 1;
            float a = 0.f;
            for (int f = 0; f < 64; ++f) a = fmaf(W2_ta[k * 64 + f], Wp_a[f * 2 + j], a);
            U[128 + u] = a;
        } else if (t < 384) {
            int u = t - 256; int k = u >> 1, j = u & 1;
            float a = 0.f;
            for (int f = 0; f < 64; ++f) a = fmaf(W2_at[k * 64 + f], Wp_t[f * 2 + j], a);
            U[256 + u] = a;
        } else if (t < 386) {
            int j = t - 384;
            float a = bp_a[j];
            for (int f = 0; f < 64; ++f) a = fmaf(b2_aa[f] + b2_ta[f], Wp_a[f * 2 + j], a);
            U[384 + j] = a;
        } else if (t < 388) {
            int j = t - 386;
            float a = bp_t[j];
            for (int f = 0; f < 64; ++f) a = fmaf(b2_at[f], Wp_t[f * 2 + j], a);
            U[386 + j] = a;
        }
    }
}

// ---------- conv1 kernel A: GATHER ONLY -> scaled agg rows to workspace. ----------
__global__ void __launch_bounds__(1024, 4)
conv1_gather_kernel(const float* __restrict__ x_a, const float* __restrict__ x_t,
                    const int* __restrict__ ro, const unsigned short* __restrict__ csr,
                    const float* __restrict__ c_aa, const float* __restrict__ c_ta_d,
                    const float* __restrict__ c_ta_s, const float* __restrict__ c_at_s,
                    const float* __restrict__ c_at_d,
                    float* __restrict__ agg_a, float* __restrict__ agg_t) {
    int lane = threadIdx.x & 63;
    int wid = threadIdx.x >> 6;      // 0..15
    int e8 = lane >> 3, k4 = lane & 7;

    if (blockIdx.x < C1_AB) {
        // ---------- agents ----------
        int i = blockIdx.x * 16 + wid;
        int b0 = ro[i], e0v = ro[i + 1];
        int b1 = ro[NA + i], e1v = ro[NA + i + 1];
        int na = e0v - b0, nt = e1v - b1;
        int sA = (lane < na) ? (int)csr[b0 + lane] : -1;
        int sT = (lane < nt) ? (int)csr[b1 + lane] : -1;
        float cAv = (sA >= 0) ? c_aa[sA] : 0.f;
        float cTv = (sT >= 0) ? c_ta_s[sT] : 0.f;

        while (true) {
            int ni = i + C1_AS;
            bool more = ni < NA;
            int nb0 = 0, ne0 = 0, nb1 = 0, ne1 = 0;
            if (more) {
                nb0 = ro[ni]; ne0 = ro[ni + 1];
                nb1 = ro[NA + ni]; ne1 = ro[NA + ni + 1];
            }
            float ci = c_aa[i], ctd = c_ta_d[i];
            float4 xs = make_float4(0.f, 0.f, 0.f, 0.f);
            if (e8 == 0) xs = *(const float4*)(x_a + (size_t)i * 32 + k4 * 4);

            float4 accA = make_float4(0.f, 0.f, 0.f, 0.f);
            float4 accT = make_float4(0.f, 0.f, 0.f, 0.f);
            int nGA = (min(na, 64) + 7) >> 3;
            int nGT = (min(nt, 64) + 7) >> 3;
            int ga = 0;
            for (; ga + 2 <= nGA; ga += 2) {
                int s0 = __shfl(sA, ga * 8 + e8, 64);
                int s1 = __shfl(sA, ga * 8 + 8 + e8, 64);
                float w0 = __shfl(cAv, ga * 8 + e8, 64);
                float w1 = __shfl(cAv, ga * 8 + 8 + e8, 64);
                float4 x0 = make_float4(0.f, 0.f, 0.f, 0.f), x1 = x0;
                if (s0 >= 0) x0 = *(const float4*)(x_a + (size_t)s0 * 32 + k4 * 4);
                if (s1 >= 0) x1 = *(const float4*)(x_a + (size_t)s1 * 32 + k4 * 4);
                accA.x = fmaf(x0.x, w0, accA.x); accA.y = fmaf(x0.y, w0, accA.y);
                accA.z = fmaf(x0.z, w0, accA.z); accA.w = fmaf(x0.w, w0, accA.w);
                accA.x = fmaf(x1.x, w1, accA.x); accA.y = fmaf(x1.y, w1, accA.y);
                accA.z = fmaf(x1.z, w1, accA.z); accA.w = fmaf(x1.w, w1, accA.w);
            }
            if (ga < nGA) {
                int s0 = __shfl(sA, ga * 8 + e8, 64);
                float w0 = __shfl(cAv, ga * 8 + e8, 64);
                float4 x0 = make_float4(0.f, 0.f, 0.f, 0.f);
                if (s0 >= 0) x0 = *(const float4*)(x_a + (size_t)s0 * 32 + k4 * 4);
                accA.x = fmaf(x0.x, w0, accA.x); accA.y = fmaf(x0.y, w0, accA.y);
                accA.z = fmaf(x0.z, w0, accA.z); accA.w = fmaf(x0.w, w0, accA.w);
            }
            for (int j = b0 + 64 + e8; j < e0v; j += 8) {
                int s = csr[j];
                float w = c_aa[s];
                float4 xv = *(const float4*)(x_a + (size_t)s * 32 + k4 * 4);
                accA.x = fmaf(xv.x, w, accA.x); accA.y = fmaf(xv.y, w, accA.y);
                accA.z = fmaf(xv.z, w, accA.z); accA.w = fmaf(xv.w, w, accA.w);
            }
            int gt = 0;
            for (; gt + 2 <= nGT; gt += 2) {
                int s0 = __shfl(sT, gt * 8 + e8, 64);
                int s1 = __shfl(sT, gt * 8 + 8 + e8, 64);
                float w0 = __shfl(cTv, gt * 8 + e8, 64);
                float w1 = __shfl(cTv, gt * 8 + 8 + e8, 64);
                float4 x0 = make_float4(0.f, 0.f, 0.f, 0.f), x1 = x0;
                if (s0 >= 0) x0 = *(const float4*)(x_t + (size_t)s0 * 32 + k4 * 4);
                if (s1 >= 0) x1 = *(const float4*)(x_t + (size_t)s1 * 32 + k4 * 4);
                accT.x = fmaf(x0.x, w0, accT.x); accT.y = fmaf(x0.y, w0, accT.y);
                accT.z = fmaf(x0.z, w0, accT.z); accT.w = fmaf(x0.w, w0, accT.w);
                accT.x = fmaf(x1.x, w1, accT.x); accT.y = fmaf(x1.y, w1, accT.y);
                accT.z = fmaf(x1.z, w1, accT.z); accT.w = fmaf(x1.w, w1, accT.w);
            }
            if (gt < nGT) {
                int s0 = __shfl(sT, gt * 8 + e8, 64);
                float w0 = __shfl(cTv, gt * 8 + e8, 64);
                float4 x0 = make_float4(0.f, 0.f, 0.f, 0.f);
                if (s0 >= 0) x0 = *(const float4*)(x_t + (size_t)s0 * 32 + k4 * 4);
                accT.x = fmaf(x0.x, w0, accT.x); accT.y = fmaf(x0.y, w0, accT.y);
                accT.z = fmaf(x0.z, w0, accT.z); accT.w = fmaf(x0.w, w0, accT.w);
            }
            for (int j = b1 + 64 + e8; j < e1v; j += 8) {
                int s = csr[j];
                float w = c_ta_s[s];
                float4 xv = *(const float4*)(x_t + (size_t)s * 32 + k4 * 4);
                accT.x = fmaf(xv.x, w, accT.x); accT.y = fmaf(xv.y, w, accT.y);
                accT.z = fmaf(xv.z, w, accT.z); accT.w = fmaf(xv.w, w, accT.w);
            }
            // self-loop
            accA.x = fmaf(xs.x, ci, accA.x); accA.y = fmaf(xs.y, ci, accA.y);
            accA.z = fmaf(xs.z, ci, accA.z); accA.w = fmaf(xs.w, ci, accA.w);

            int nsA = -1, nsT = -1;
            if (more) {
                int nna = ne0 - nb0, nnt = ne1 - nb1;
                nsA = (lane < nna) ? (int)csr[nb0 + lane] : -1;
                nsT = (lane < nnt) ? (int)csr[nb1 + lane] : -1;
            }

#pragma unroll
            for (int m = 8; m <= 32; m <<= 1) {
                accA.x += __shfl_xor(accA.x, m, 64);
                accA.y += __shfl_xor(accA.y, m, 64);
                accA.z += __shfl_xor(accA.z, m, 64);
                accA.w += __shfl_xor(accA.w, m, 64);
                accT.x += __shfl_xor(accT.x, m, 64);
                accT.y += __shfl_xor(accT.y, m, 64);
                accT.z += __shfl_xor(accT.z, m, 64);
                accT.w += __shfl_xor(accT.w, m, 64);
            }

            float ncA = 0.f, ncT = 0.f;
            if (more) {
                ncA = (nsA >= 0) ? c_aa[nsA] : 0.f;
                ncT = (nsT >= 0) ? c_ta_s[nsT] : 0.f;
            }

            if (e8 == 0) {
                *(float4*)(agg_a + (size_t)i * 64 + k4 * 4) =
                    make_float4(accA.x * ci, accA.y * ci, accA.z * ci, accA.w * ci);
                *(float4*)(agg_a + (size_t)i * 64 + 32 + k4 * 4) =
                    make_float4(accT.x * ctd, accT.y * ctd, accT.z * ctd, accT.w * ctd);
            }

            if (!more) break;
            i = ni;
            b0 = nb0; e0v = ne0; b1 = nb1; e1v = ne1;
            na = ne0 - nb0; nt = ne1 - nb1;
            sA = nsA; sT = nsT; cAv = ncA; cTv = ncT;
        }
    } else {
        // ---------- targets ----------
        int i = (blockIdx.x - C1_AB) * 16 + wid;
        int b0 = ro[2 * NA + i], e0v = ro[2 * NA + i + 1];
        int na = e0v - b0;
        int sA = (lane < na) ? (int)csr[b0 + lane] : -1;
        float cAv = (sA >= 0) ? c_at_s[sA] : 0.f;

        while (true) {
            int ni = i + C1_TS;
            bool more = ni < NT;
            int nb0 = 0, ne0 = 0;
            if (more) { nb0 = ro[2 * NA + ni]; ne0 = ro[2 * NA + ni + 1]; }
            float cd = c_at_d[i];

            float4 acc = make_float4(0.f, 0.f, 0.f, 0.f);
            int nG = (min(na, 64) + 7) >> 3;
            int ga = 0;
            for (; ga + 2 <= nG; ga += 2) {
                int s0 = __shfl(sA, ga * 8 + e8, 64);
                int s1 = __shfl(sA, ga * 8 + 8 + e8, 64);
                float w0 = __shfl(cAv, ga * 8 + e8, 64);
                float w1 = __shfl(cAv, ga * 8 + 8 + e8, 64);
                float4 x0 = make_float4(0.f, 0.f, 0.f, 0.f), x1 = x0;
                if (s0 >= 0) x0 = *(const float4*)(x_a + (size_t)s0 * 32 + k4 * 4);
                if (s1 >= 0) x1 = *(const float4*)(x_a + (size_t)s1 * 32 + k4 * 4);
                acc.x = fmaf(x0.x, w0, acc.x); acc.y = fmaf(x0.y, w0, acc.y);
                acc.z = fmaf(x0.z, w0, acc.z); acc.w = fmaf(x0.w, w0, acc.w);
                acc.x = fmaf(x1.x, w1, acc.x); acc.y = fmaf(x1.y, w1, acc.y);
                acc.z = fmaf(x1.z, w1, acc.z); acc.w = fmaf(x1.w, w1, acc.w);
            }
            if (ga < nG) {
                int s0 = __shfl(sA, ga * 8 + e8, 64);
                float w0 = __shfl(cAv, ga * 8 + e8, 64);
                float4 x0 = make_float4(0.f, 0.f, 0.f, 0.f);
                if (s0 >= 0) x0 = *(const float4*)(x_a + (size_t)s0 * 32 + k4 * 4);
                acc.x = fmaf(x0.x, w0, acc.x); acc.y = fmaf(x0.y, w0, acc.y);
                acc.z = fmaf(x0.z, w0, acc.z); acc.w = fmaf(x0.w, w0, acc.w);
            }
            for (int j = b0 + 64 + e8; j < e0v; j += 8) {
                int s = csr[j];
                float w = c_at_s[s];
                float4 xv = *(const float4*)(x_a + (size_t)s * 32 + k4 * 4);
                acc.x = fmaf(xv.x, w, acc.x); acc.y = fmaf(xv.y, w, acc.y);
                acc.z = fmaf(xv.z, w, acc.z); acc.w = fmaf(xv.w, w, acc.w);
            }

            int nsA = -1;
            if (more) {
                int nna = ne0 - nb0;
                nsA = (lane < nna) ? (int)csr[nb0 + lane] : -1;
            }

#pragma unroll
            for (int m = 8; m <= 32; m <<= 1) {
                acc.x += __shfl_xor(acc.x, m, 64);
                acc.y += __shfl_xor(acc.y, m, 64);
                acc.z += __shfl_xor(acc.z, m, 64);
                acc.w += __shfl_xor(acc.w, m, 64);
            }

            float ncA = 0.f;
            if (more) ncA = (nsA >= 0) ? c_at_s[nsA] : 0.f;

            if (e8 == 0) {
                *(float4*)(agg_t + (size_t)i * 32 + k4 * 4) =
                    make_float4(acc.x * cd, acc.y * cd, acc.z * cd, acc.w * cd);
            }

            if (!more) break;
            i = ni;
            b0 = nb0; e0v = ne0; na = ne0 - nb0;
            sA = nsA; cAv = ncA;
        }
    }
}

// ---------- kernel B: dense transform + fused projection ----------
__global__ void __launch_bounds__(256)
dense_b_kernel(const float* __restrict__ agg_a, const float* __restrict__ agg_t,
               const float* __restrict__ W_aa, const float* __restrict__ W_ta,
               const float* __restrict__ W_at,
               const float* __restrict__ b_aa, const float* __restrict__ b_ta,
               const float* __restrict__ b_at, const float* __restrict__ U,
               const float* __restrict__ c_aa, const float* __restrict__ c_at_s,
               const float* __restrict__ c_ta_s,
               float* __restrict__ p, float* __restrict__ q, float* __restrict__ r) {
    __shared__ float Wc[64 * 68];    // Wc[k*68+f]
    __shared__ float AG[64 * 68];    // AG[n*68+k]
    __shared__ float BI[64];
    __shared__ float UP0[64], UP1[64], UQ0[64], UQ1[64];
    int t = threadIdx.x;
    int nloc = t >> 2;               // 0..63: node within tile
    int f0 = (t & 3) << 4;           // 0,16,32,48

    if (blockIdx.x < NBB_A) {
        for (int idx = t; idx < 4096; idx += 256) {
            int k = idx >> 6, f = idx & 63;
            Wc[k * 68 + f] = (k < 32) ? W_aa[k * 64 + f] : W_ta[(k - 32) * 64 + f];
        }
        if (t < 64) {
            BI[t] = b_aa[t] + b_ta[t];
            UP0[t] = U[t * 2];       UP1[t] = U[t * 2 + 1];
            UQ0[t] = U[256 + t * 2]; UQ1[t] = U[256 + t * 2 + 1];
        }
        int t0 = blockIdx.x * 64;
        for (int idx = t; idx < 1024; idx += 256) {
            int n = idx >> 4, kq = idx & 15;
            int gi = t0 + n;
            float4 v = make_float4(0.f, 0.f, 0.f, 0.f);
            if (gi < NA) v = *(const float4*)(agg_a + (size_t)gi * 64 + kq * 4);
            *(float4*)&AG[n * 68 + kq * 4] = v;
        }
        __syncthreads();

        float4 h0 = *(const float4*)&BI[f0];
        float4 h1 = *(const float4*)&BI[f0 + 4];
        float4 h2 = *(const float4*)&BI[f0 + 8];
        float4 h3 = *(const float4*)&BI[f0 + 12];
        const float* ag = &AG[nloc * 68];
#pragma unroll 8
        for (int k = 0; k < 64; ++k) {
            float a = ag[k];
            const float* w = &Wc[k * 68 + f0];
            float4 w0 = *(const float4*)(w);
            float4 w1 = *(const float4*)(w + 4);
            float4 w2 = *(const float4*)(w + 8);
            float4 w3 = *(const float4*)(w + 12);
            h0.x = fmaf(a, w0.x, h0.x); h0.y = fmaf(a, w0.y, h0.y);
            h0.z = fmaf(a, w0.z, h0.z); h0.w = fmaf(a, w0.w, h0.w);
            h1.x = fmaf(a, w1.x, h1.x); h1.y = fmaf(a, w1.y, h1.y);
            h1.z = fmaf(a, w1.z, h1.z); h1.w = fmaf(a, w1.w, h1.w);
            h2.x = fmaf(a, w2.x, h2.x); h2.y = fmaf(a, w2.y, h2.y);
            h2.z = fmaf(a, w2.z, h2.z); h2.w = fmaf(a, w2.w, h2.w);
            h3.x = fmaf(a, w3.x, h3.x); h3.y = fmaf(a, w3.y, h3.y);
            h3.z = fmaf(a, w3.z, h3.z); h3.w = fmaf(a, w3.w, h3.w);
        }
        float hv[16];
        hv[0] = fmaxf(h0.x, 0.f); hv[1] = fmaxf(h0.y, 0.f);
        hv[2] = fmaxf(h0.z, 0.f); hv[3] = fmaxf(h0.w, 0.f);
        hv[4] = fmaxf(h1.x, 0.f); hv[5] = fmaxf(h1.y, 0.f);
        hv[6] = fmaxf(h1.z, 0.f); hv[7] = fmaxf(h1.w, 0.f);
        hv[8] = fmaxf(h2.x, 0.f); hv[9] = fmaxf(h2.y, 0.f);
        hv[10] = fmaxf(h2.z, 0.f); hv[11] = fmaxf(h2.w, 0.f);
        hv[12] = fmaxf(h3.x, 0.f); hv[13] = fmaxf(h3.y, 0.f);
        hv[14] = fmaxf(h3.z, 0.f); hv[15] = fmaxf(h3.w, 0.f);
        float p0 = 0.f, p1 = 0.f, q0 = 0.f, q1 = 0.f;
#pragma unroll
        for (int ii = 0; ii < 16; ++ii) {
            int f = f0 + ii;
            p0 = fmaf(hv[ii], UP0[f], p0);
            p1 = fmaf(hv[ii], UP1[f], p1);
            q0 = fmaf(hv[ii], UQ0[f], q0);
            q1 = fmaf(hv[ii], UQ1[f], q1);
        }
        p0 += __shfl_xor(p0, 1, 64); p0 += __shfl_xor(p0, 2, 64);
        p1 += __shfl_xor(p1, 1, 64); p1 += __shfl_xor(p1, 2, 64);
        q0 += __shfl_xor(q0, 1, 64); q0 += __shfl_xor(q0, 2, 64);
        q1 += __shfl_xor(q1, 1, 64); q1 += __shfl_xor(q1, 2, 64);
        int gi = t0 + nloc;
        if ((t & 3) == 0 && gi < NA) {
            float ci = c_aa[gi], cq = c_at_s[gi];
            *(float2*)&p[gi * 2] = make_float2(p0 * ci, p1 * ci);
            *(float2*)&q[gi * 2] = make_float2(q0 * cq, q1 * cq);
        }
    } else {
        for (int idx = t; idx < 2048; idx += 256) {
            int k = idx >> 6, f = idx & 63;
            Wc[k * 68 + f] = W_at[k * 64 + f];
        }
        if (t < 64) {
            BI[t] = b_at[t];
            UP0[t] = U[128 + t * 2]; UP1[t] = U[128 + t * 2 + 1];
        }
        int t0 = (blockIdx.x - NBB_A) * 64;
        for (int idx = t; idx < 512; idx += 256) {
            int n = idx >> 3, kq = idx & 7;
            int gi = t0 + n;
            float4 v = make_float4(0.f, 0.f, 0.f, 0.f);
            if (gi < NT) v = *(const float4*)(agg_t + (size_t)gi * 32 + kq * 4);
            *(float4*)&AG[n * 68 + kq * 4] = v;
        }
        __syncthreads();

        float4 h0 = *(const float4*)&BI[f0];
        float4 h1 = *(const float4*)&BI[f0 + 4];
        float4 h2 = *(const float4*)&BI[f0 + 8];
        float4 h3 = *(const float4*)&BI[f0 + 12];
        const float* ag = &AG[nloc * 68];
#pragma unroll 8
        for (int k = 0; k < 32; ++k) {
            float a = ag[k];
            const float* w = &Wc[k * 68 + f0];
            float4 w0 = *(const float4*)(w);
            float4 w1 = *(const float4*)(w + 4);
            float4 w2 = *(const float4*)(w + 8);
            float4 w3 = *(const float4*)(w + 12);
            h0.x = fmaf(a, w0.x, h0.x); h0.y = fmaf(a, w0.y, h0.y);
            h0.z = fmaf(a, w0.z, h0.z); h0.w = fmaf(a, w0.w, h0.w);
            h1.x = fmaf(a, w1.x, h1.x); h1.y = fmaf(a, w1.y, h1.y);
            h1.z = fmaf(a, w1.z, h1.z); h1.w = fmaf(a, w1.w, h1.w);
            h2.x = fmaf(a, w2.x, h2.x); h2.y = fmaf(a, w2.y, h2.y);
            h2.z = fmaf(a, w2.z, h2.z); h2.w = fmaf(a, w2.w, h2.w);
            h3.x = fmaf(a, w3.x, h3.x); h3.y = fmaf(a, w3.y, h3.y);
            h3.z = fmaf(a, w3.z, h3.z); h3.w = fmaf(a, w3.w, h3.w);
        }
        float hv[16];
        hv[0] = fmaxf(h0.x, 0.f); hv[1] = fmaxf(h0.y, 0.f);
        hv[2] = fmaxf(h0.z, 0.f); hv[3] = fmaxf(h0.w, 0.f);
        hv[4] = fmaxf(h1.x, 0.f); hv[5] = fmaxf(h1.y, 0.f);
        hv[6] = fmaxf(h1.z, 0.f); hv[7] = fmaxf(h1.w, 0.f);
        hv[8] = fmaxf(h2.x, 0.f); hv[9] = fmaxf(h2.y, 0.f);
        hv[10] = fmaxf(h2.z, 0.f); hv[11] = fmaxf(h2.w, 0.f);
        hv[12] = fmaxf(h3.x, 0.f); hv[13] = fmaxf(h3.y, 0.f);
        hv[14] = fmaxf(h3.z, 0.f); hv[15] = fmaxf(h3.w, 0.f);
        float r0 = 0.f, r1 = 0.f;
#pragma unroll
        for (int ii = 0; ii < 16; ++ii) {
            int f = f0 + ii;
            r0 = fmaf(hv[ii], UP0[f], r0);
            r1 = fmaf(hv[ii], UP1[f], r1);
        }
        r0 += __shfl_xor(r0, 1, 64); r0 += __shfl_xor(r0, 2, 64);
        r1 += __shfl_xor(r1, 1, 64); r1 += __shfl_xor(r1, 2, 64);
        int gi = t0 + nloc;
        if ((t & 3) == 0 && gi < NT) {
            float cr = c_ta_s[gi];
            *(float2*)&r[gi * 2] = make_float2(r0 * cr, r1 * cr);
        }
    }
}

// ---------- conv2+proj: one wave per node, 32 edge slots x 2 comps ----------
__global__ void __launch_bounds__(256)
out_all_kernel(const float* __restrict__ p, const float* __restrict__ q,
               const float* __restrict__ r, const int* __restrict__ ro,
               const unsigned short* __restrict__ csr,
               const float* __restrict__ c_aa, const float* __restrict__ c_ta_d,
               const float* __restrict__ c_at_d, const float* __restrict__ U,
               float* __restrict__ out) {
    int wgid = blockIdx.x * 4 + (threadIdx.x >> 6);
    int lane = threadIdx.x & 63;
    int slot = lane >> 1, j = lane & 1;
    if (wgid < NA) {
        int i = wgid;
        int b0 = ro[i], n0 = ro[i + 1] - b0;
        float accA = (slot == 0) ? p[i * 2 + j] : 0.f;
        for (int e = slot; e < n0; e += 32) accA += p[(int)csr[b0 + e] * 2 + j];
        int b1 = ro[NA + i], n1 = ro[NA + i + 1] - b1;
        float accT = 0.f;
        for (int e = slot; e < n1; e += 32) accT += r[(int)csr[b1 + e] * 2 + j];
#pragma unroll
        for (int m = 2; m <= 32; m <<= 1) {
            accA += __shfl_xor(accA, m, 64);
            accT += __shfl_xor(accT, m, 64);
        }
        if (lane < 2) out[i * 2 + j] = U[384 + j] + accA * c_aa[i] + accT * c_ta_d[i];
    } else {
        int i = wgid - NA;
        int b0 = ro[2 * NA + i], n0 = ro[2 * NA + i + 1] - b0;
        float acc = 0.f;
        for (int e = slot; e < n0; e += 32) acc += q[(int)csr[b0 + e] * 2 + j];
#pragma unroll
        for (int m = 2; m <= 32; m <<= 1) acc += __shfl_xor(acc, m, 64);
        if (lane < 2) out[NA * 2 + i * 2 + j] = U[386 + j] + acc * c_at_d[i];
    }
}

extern "C" void kernel_launch(void* const* d_in, const int* in_sizes, int n_in,
                              void* d_out, int out_size, void* d_ws, size_t ws_size,
                              hipStream_t stream) {
    const float* x_a   = (const float*)d_in[1];
    const float* x_t   = (const float*)d_in[2];
    const int* src_aa  = (const int*)d_in[3];
    const int* dst_aa  = (const int*)d_in[4];
    const int* src_at  = (const int*)d_in[5];
    const int* dst_at  = (const int*)d_in[6];
    const int* src_ta  = (const int*)d_in[7];
    const int* dst_ta  = (const int*)d_in[8];
    const float* W1_aa = (const float*)d_in[9];
    const float* b1_aa = (const float*)d_in[10];
    const float* W1_at = (const float*)d_in[11];
    const float* b1_at = (const float*)d_in[12];
    const float* W1_ta = (const float*)d_in[13];
    const float* b1_ta = (const float*)d_in[14];
    const float* W2_aa = (const float*)d_in[15];
    const float* b2_aa = (const float*)d_in[16];
    const float* W2_at = (const float*)d_in[17];
    const float* b2_at = (const float*)d_in[18];
    const float* W2_ta = (const float*)d_in[19];
    const float* b2_ta = (const float*)d_in[20];
    const float* Wp_a  = (const float*)d_in[21];
    const float* bp_a  = (const float*)d_in[22];
    const float* Wp_t  = (const float*)d_in[23];
    const float* bp_t  = (const float*)d_in[24];

    int*   wi  = (int*)d_ws;
    float* wf  = (float*)d_ws;
    unsigned short* csr = (unsigned short*)(wi + O_CSR);
    float* out = (float*)d_out;

    // single memset: striped src histograms + adjacent striped/padded slab counters
    hipMemsetAsync(wi + O_SRCH, 0, (size_t)(8 * SRCH_STRIDE + 8 * NB * 16) * 4, stream);

    // pass 1 v4: register-held edges, CHUNK=8192 -> full-line slab runs
    p1_fused_kernel<<<NBLK1, 1024, 0, stream>>>(src_aa, dst_aa, src_ta, dst_ta,
                                                src_at, dst_at, wi);

    // fused pass 2 + aux: p2 (flattened 8-sub-slab loops) | src coefs | U fuse
    p2_aux_kernel<<<NB + 75, 1024, 0, stream>>>(wi, wf, W2_aa, W2_ta, W2_at,
                                                b2_aa, b2_ta, b2_at,
                                                Wp_a, bp_a, Wp_t, bp_t);

    // conv1-A: gather -> scaled agg rows (AGG overlays dead REC region)
    conv1_gather_kernel<<<C1_AB + C1_TB, 1024, 0, stream>>>(
        x_a, x_t, wi + O_RO, csr,
        wf + O_CAA, wf + O_CTAD, wf + O_CTAS, wf + O_CATS, wf + O_CATD,
        wf + O_AGA, wf + O_AGT);

    // conv1-B: dense transform + fused projections
    dense_b_kernel<<<NBB_A + NBB_T, 256, 0, stream>>>(
        wf + O_AGA, wf + O_AGT,
        W1_aa, W1_ta, W1_at, b1_aa, b1_ta, b1_at, wf + O_U,
        wf + O_CAA, wf + O_CATS, wf + O_CTAS,
        wf + O_P, wf + O_Q, wf + O_R);

    // conv2 + projection, wave per node
    out_all_kernel<<<(NA + NT) / 4, 256, 0, stream>>>(
        wf + O_P, wf + O_Q, wf + O_R, wi + O_RO, csr,
        wf + O_CAA, wf + O_CTAD, wf + O_CATD, wf + O_U, out);
}